// Round 5
// baseline (112.982 us; speedup 1.0000x reference)
//
#include <hip/hip_runtime.h>

// SimpleGCNConv: out = rownorm(setadj(ei) + I) @ x @ W^T + b
// N=8192, E=262144, D=128, fp32.
// R5 restructure using associativity: out = D^-1 (A+I) (x W^T) + b.
//   K0  memset bitmap+cnt+zrow (hipMemsetAsync)
//   K1a scatter: atomicOr dedup; winners append to per-node list.
//       + spare blocks transpose W -> Wt (coalesced GEMM operand).
//   K1b z = x @ W^T  (268 MFLOP, compute-bound ~3 us)
//   K2  gather z rows via lists, normalize, +b  (pure gather, 100% occ)

typedef unsigned int uint32;

#define NNODES 8192
#define DF 128
#define DF4 (DF / 4)
#define WPR 256                 // bitmap words per row
#define CAP 128                 // list capacity (deg ~ Poisson(32), max ~70)
#define M 4                     // nodes per gather block

#define BM_BYTES  ((size_t)NNODES * WPR * 4)            // 8 MB
#define CNT_OFF   BM_BYTES
#define ZROW_OFF  (CNT_OFF + (size_t)NNODES * 4)
#define LIST_OFF  (ZROW_OFF + 1024)
#define WT_OFF    (LIST_OFF + (size_t)NNODES * CAP * 4) // 4 MB list
#define Z_OFF     (WT_OFF + (size_t)DF * DF * 4)

__device__ __forceinline__ float4 f4add(float4 a, float4 b) {
    return make_float4(a.x + b.x, a.y + b.y, a.z + b.z, a.w + b.w);
}

// K1a: dedup-scatter (blocks [0, nsb)) + W transpose (blocks [nsb, nsb+16)).
__global__ __launch_bounds__(256) void scatter_transpose(
    const int* __restrict__ ei, int E, const float* __restrict__ W,
    uint32* __restrict__ bm, int* __restrict__ cnt,
    int* __restrict__ list, float* __restrict__ Wt)
{
    const int blk = blockIdx.x, t = threadIdx.x;
    const int nsb = (E + 255) >> 8;
    if (blk < nsb) {
        int e = blk * 256 + t;
        if (e < E) {
            int src = ei[e];
            int dst = ei[E + e];
            uint32 m = 1u << (dst & 31);
            uint32 old = atomicOr(&bm[(size_t)src * WPR + (dst >> 5)], m);
            if (!(old & m)) {                       // first time this (src,dst)
                int p = atomicAdd(&cnt[src], 1);
                if (p < CAP) list[src * CAP + p] = dst;
            }
        }
    } else {
        // transpose: Wt[k*DF+d] = W[d*DF+k]; 16 blocks x 256 thr x 4 elems
        for (int i = (blk - nsb) * 256 + t; i < DF * DF; i += 16 * 256) {
            int k = i >> 7, d = i & (DF - 1);
            Wt[i] = W[d * DF + k];
        }
    }
}

// K1b: z[n][d] = sum_k x[n][k] * Wt[k][d].  32 nodes/block, 256 blocks.
// Thread (ng=t>>5, c=t&31) computes nodes 4ng..4ng+3, dims 4c..4c+3.
__global__ __launch_bounds__(256) void node_gemm(
    const float* __restrict__ x, const float* __restrict__ Wt,
    float* __restrict__ z)
{
    __shared__ float xs[32][DF];                    // 16 KB
    const int t = threadIdx.x;
    const int n0 = blockIdx.x * 32;

    const float4* x4 = (const float4*)x + (size_t)n0 * DF4;
    float4* xs4 = (float4*)xs;
    for (int i = t; i < 32 * DF4; i += 256) xs4[i] = x4[i];
    __syncthreads();

    const int c = t & 31;
    const int ng = t >> 5;
    const float4* Wt4 = (const float4*)Wt;

    float4 a0 = make_float4(0, 0, 0, 0), a1 = a0, a2 = a0, a3 = a0;
    #pragma unroll 4
    for (int k = 0; k < DF; ++k) {
        float4 wv = Wt4[k * DF4 + c];               // coalesced, L1/L2
        float x0 = xs[4 * ng + 0][k];               // LDS broadcast
        float x1 = xs[4 * ng + 1][k];
        float x2 = xs[4 * ng + 2][k];
        float x3 = xs[4 * ng + 3][k];
        a0.x += x0 * wv.x; a0.y += x0 * wv.y; a0.z += x0 * wv.z; a0.w += x0 * wv.w;
        a1.x += x1 * wv.x; a1.y += x1 * wv.y; a1.z += x1 * wv.z; a1.w += x1 * wv.w;
        a2.x += x2 * wv.x; a2.y += x2 * wv.y; a2.z += x2 * wv.z; a2.w += x2 * wv.w;
        a3.x += x3 * wv.x; a3.y += x3 * wv.y; a3.z += x3 * wv.z; a3.w += x3 * wv.w;
    }
    float4* z4 = (float4*)z;
    z4[(size_t)(n0 + 4 * ng + 0) * DF4 + c] = a0;
    z4[(size_t)(n0 + 4 * ng + 1) * DF4 + c] = a1;
    z4[(size_t)(n0 + 4 * ng + 2) * DF4 + c] = a2;
    z4[(size_t)(n0 + 4 * ng + 3) * DF4 + c] = a3;
}

// K2: out[i] = (sum_{j in nbr(i)} z[j] + z[i]) / (deg_i+1) + b.
// M=4 nodes/block, 256 threads, grid 2048 -> 8 blocks/CU, 32 waves/CU.
__global__ __launch_bounds__(256) void gather_out(
    const float* __restrict__ z, const uint32* __restrict__ bm,
    const int* __restrict__ cnt, const int* __restrict__ list,
    const float4* __restrict__ zrow, const float* __restrict__ b,
    float* __restrict__ out)
{
    __shared__ int   nbr[M][CAP];                   // 2 KB
    __shared__ int   cs[M];
    __shared__ float4 part[M][4][32];               // 8 KB

    const int t = threadIdx.x;
    const int node0 = blockIdx.x * M;
    const int w = t >> 6, lane = t & 63;
    const int g = t >> 5, c = t & 31;

    if (t < M) cs[t] = cnt[node0 + t];
    __syncthreads();

    // Stage lists: wave w handles node w; pad beyond count with -1.
    {
        const int cm = min(cs[w], CAP);
        const int base = (node0 + w) * CAP;
        nbr[w][lane]      = (lane      < cm) ? list[base + lane]      : -1;
        nbr[w][lane + 64] = (lane + 64 < cm) ? list[base + lane + 64] : -1;
    }
    __syncthreads();

    const int Lmax = max(max(min(cs[0], CAP), min(cs[1], CAP)),
                         max(min(cs[2], CAP), min(cs[3], CAP)));
    const int Lpad = (Lmax + 7) & ~7;

    // Gather: group g takes k === g (mod 8); M chains interleaved.
    const float4* z4 = (const float4*)z;
    float4 acc[M];
    #pragma unroll
    for (int m = 0; m < M; ++m) acc[m] = make_float4(0, 0, 0, 0);

    for (int k = g; k < Lpad; k += 8) {
        #pragma unroll
        for (int m = 0; m < M; ++m) {
            int j = nbr[m][k];
            const float4* p = (j >= 0) ? (z4 + (size_t)j * DF4 + c)
                                       : (zrow + c);
            acc[m] = f4add(acc[m], *p);
        }
    }

    // Combine the wave's two groups (same m, same c, lanes L and L+32).
    #pragma unroll
    for (int m = 0; m < M; ++m) {
        acc[m].x += __shfl_down(acc[m].x, 32);
        acc[m].y += __shfl_down(acc[m].y, 32);
        acc[m].z += __shfl_down(acc[m].z, 32);
        acc[m].w += __shfl_down(acc[m].w, 32);
    }
    if (lane < 32) {
        #pragma unroll
        for (int m = 0; m < M; ++m) part[m][w][c] = acc[m];
    }
    __syncthreads();

    // Final: thread t<128 owns (m = t>>5, chunk c); float4 store.
    if (t < 128) {
        const int m = t >> 5;
        const int cm = cs[m];
        const float4* b4 = (const float4*)b;
        float4* out4 = (float4*)out;
        if (cm <= CAP) {
            float4 s = f4add(f4add(part[m][0][c], part[m][1][c]),
                             f4add(part[m][2][c], part[m][3][c]));
            s = f4add(s, z4[(size_t)(node0 + m) * DF4 + c]);   // self-loop
            float inv = 1.0f / (float)(cm + 1);
            float4 bb = b4[c];
            float4 o = make_float4(s.x * inv + bb.x, s.y * inv + bb.y,
                                   s.z * inv + bb.z, s.w * inv + bb.w);
            out4[(size_t)(node0 + m) * DF4 + c] = o;
        } else {
            // Overflow fallback (statistically never): bitmap rescan.
            float4 a = z4[(size_t)(node0 + m) * DF4 + c];
            const uint32* r = bm + (size_t)(node0 + m) * WPR;
            for (int wd = 0; wd < WPR; ++wd) {
                uint32 word = r[wd];
                int base = wd << 5;
                while (word) {
                    int bit = __ffs(word) - 1; word &= word - 1;
                    a = f4add(a, z4[(size_t)(base + bit) * DF4 + c]);
                }
            }
            float inv = 1.0f / (float)(cm + 1);
            float4 bb = b4[c];
            out4[(size_t)(node0 + m) * DF4 + c] =
                make_float4(a.x * inv + bb.x, a.y * inv + bb.y,
                            a.z * inv + bb.z, a.w * inv + bb.w);
        }
    }
}

extern "C" void kernel_launch(void* const* d_in, const int* in_sizes, int n_in,
                              void* d_out, int out_size, void* d_ws, size_t ws_size,
                              hipStream_t stream) {
    const float* x = (const float*)d_in[0];
    const int*  ei = (const int*)d_in[1];
    const float* W = (const float*)d_in[2];
    const float* b = (const float*)d_in[3];
    float* out = (float*)d_out;

    char* ws = (char*)d_ws;
    uint32* bm   = (uint32*)ws;
    int*    cnt  = (int*)(ws + CNT_OFF);
    float4* zrow = (float4*)(ws + ZROW_OFF);
    int*    list = (int*)(ws + LIST_OFF);
    float*  Wt   = (float*)(ws + WT_OFF);
    float*  z    = (float*)(ws + Z_OFF);

    const int E = in_sizes[1] / 2;
    const int nsb = (E + 255) / 256;

    // Zero bitmap + cnt + zrow (d_ws is re-poisoned before every launch).
    hipMemsetAsync(d_ws, 0, LIST_OFF, stream);

    scatter_transpose<<<dim3(nsb + 16), dim3(256), 0, stream>>>(
        ei, E, W, bm, cnt, list, Wt);
    node_gemm<<<dim3(NNODES / 32), dim3(256), 0, stream>>>(x, Wt, z);
    gather_out<<<dim3(NNODES / M), dim3(256), 0, stream>>>(
        z, bm, cnt, list, zrow, b, out);
}

// Round 7
// 112.797 us; speedup vs baseline: 1.0016x; 1.0016x over previous
//
#include <hip/hip_runtime.h>

// SimpleGCNConv: out = rownorm(setadj(ei) + I) @ x @ W^T + b
// N=8192, E=262144, D=128, fp32.
// R7: 3 dispatches (proven structure from R4) with list-build moved into
// the scatter (dedup winners append) and R6's gather/linear fused kernel.
//   K0 hipMemsetAsync: bitmap (8 MB) + cnt (32 KB) + zrow (contiguous)
//   K1 scatter: atomicOr dedup -> winners append to per-node lists
//   K2 8 nodes/block: LDS lists -> float4 gather (8 in flight/thread)
//      -> normalize -> fused x@W^T + b matvec.
// Cooperative single-kernel variant (R6) failed to launch (grid at the
// co-residency limit) -- multi-dispatch is the reliable path.

typedef unsigned int uint32;

#define NNODES 8192
#define DF 128
#define DF4 (DF / 4)
#define WPR 256                 // bitmap words per row
#define CAP 128                 // list cap (deg ~ Poisson(32), max ~70)

#define BM_BYTES  ((size_t)NNODES * WPR * 4)          // 8 MB
#define CNT_OFF   BM_BYTES
#define ZROW_OFF  (CNT_OFF + (size_t)NNODES * 4)      // +32 KB
#define LIST_OFF  (ZROW_OFF + 1024)                   // zrow: 512 B used
#define ZERO_BYTES LIST_OFF                           // zero bm+cnt+zrow

__device__ __forceinline__ float4 f4add(float4 a, float4 b) {
    return make_float4(a.x + b.x, a.y + b.y, a.z + b.z, a.w + b.w);
}

// K1: dedup scatter + list append. 1 edge/thread.
__global__ __launch_bounds__(256) void scatter_dedup(
    const int* __restrict__ ei, int E,
    uint32* __restrict__ bm, int* __restrict__ cnt, int* __restrict__ list)
{
    int e = blockIdx.x * 256 + threadIdx.x;
    if (e >= E) return;
    int src = ei[e];
    int dst = ei[E + e];
    uint32 m = 1u << (dst & 31);
    uint32 old = atomicOr(&bm[(size_t)src * WPR + (dst >> 5)], m);
    if (!(old & m)) {                                 // first (src,dst)
        int p = atomicAdd(&cnt[src], 1);
        if (p < CAP) list[src * CAP + p] = dst;
    }
}

// K2: 8 nodes/block; gather + normalize + fused linear.
__global__ __launch_bounds__(256, 4) void gcn_gather(
    const float* __restrict__ x, const float* __restrict__ W,
    const float* __restrict__ b, const uint32* __restrict__ bm,
    const int* __restrict__ cnt, const float4* __restrict__ zrow,
    const int* __restrict__ list, float* __restrict__ out)
{
    __shared__ int   nbr[8][CAP];                     // 4 KB
    __shared__ int   cs[8];
    __shared__ float part[8][4][DF];                  // 16 KB
    __shared__ float agg[8][DF];                      // 4 KB

    const int t = threadIdx.x;
    const int node0 = blockIdx.x * 8;
    if (t < 8) cs[t] = cnt[node0 + t];
    __syncthreads();

    // Stage lists into LDS, pad to CAP with -1 (sentinel -> zero row).
    {
        const int m = t >> 5, l = t & 31;
        const int cm = min(cs[m], CAP);
        const int base = (node0 + m) * CAP;
        #pragma unroll
        for (int q = 0; q < CAP / 32; ++q) {
            int k = l + 32 * q;
            nbr[m][k] = (k < cm) ? list[base + k] : -1;
        }
    }
    __syncthreads();

    // Half-block layout: threads 0-127 -> nodes 0-3, 128-255 -> nodes 4-7.
    const int h  = t >> 7;
    const int th = t & 127;
    const int g  = th >> 5;        // group 0..3 takes k === g (mod 4)
    const int c  = th & 31;        // float4 chunk
    const int m0 = h * 4;

    int L = 0;
    #pragma unroll
    for (int m = 0; m < 4; ++m) L = max(L, min(cs[m0 + m], CAP));
    L = (L + 7) & ~7;              // unroll-2 padding (nbr is -1-padded)

    const float4* x4 = (const float4*)x;
    float4 a0 = make_float4(0.f, 0.f, 0.f, 0.f), a1 = a0, a2 = a0, a3 = a0;

    for (int k = g; k < L; k += 8) {                  // 8 loads in flight
        int ja0 = nbr[m0 + 0][k],     ja1 = nbr[m0 + 1][k],
            ja2 = nbr[m0 + 2][k],     ja3 = nbr[m0 + 3][k];
        int jb0 = nbr[m0 + 0][k + 4], jb1 = nbr[m0 + 1][k + 4],
            jb2 = nbr[m0 + 2][k + 4], jb3 = nbr[m0 + 3][k + 4];
        const float4* pa0 = (ja0 >= 0) ? x4 + (size_t)ja0 * DF4 + c : zrow + c;
        const float4* pa1 = (ja1 >= 0) ? x4 + (size_t)ja1 * DF4 + c : zrow + c;
        const float4* pa2 = (ja2 >= 0) ? x4 + (size_t)ja2 * DF4 + c : zrow + c;
        const float4* pa3 = (ja3 >= 0) ? x4 + (size_t)ja3 * DF4 + c : zrow + c;
        const float4* pb0 = (jb0 >= 0) ? x4 + (size_t)jb0 * DF4 + c : zrow + c;
        const float4* pb1 = (jb1 >= 0) ? x4 + (size_t)jb1 * DF4 + c : zrow + c;
        const float4* pb2 = (jb2 >= 0) ? x4 + (size_t)jb2 * DF4 + c : zrow + c;
        const float4* pb3 = (jb3 >= 0) ? x4 + (size_t)jb3 * DF4 + c : zrow + c;
        float4 va0 = *pa0, va1 = *pa1, va2 = *pa2, va3 = *pa3;
        float4 vb0 = *pb0, vb1 = *pb1, vb2 = *pb2, vb3 = *pb3;
        a0 = f4add(a0, f4add(va0, vb0));
        a1 = f4add(a1, f4add(va1, vb1));
        a2 = f4add(a2, f4add(va2, vb2));
        a3 = f4add(a3, f4add(va3, vb3));
    }

    *(float4*)&part[m0 + 0][g][c * 4] = a0;
    *(float4*)&part[m0 + 1][g][c * 4] = a1;
    *(float4*)&part[m0 + 2][g][c * 4] = a2;
    *(float4*)&part[m0 + 3][g][c * 4] = a3;
    __syncthreads();

    // Combine groups, add self-loop (eye on top), normalize.
    {
        const int d = th;
        #pragma unroll
        for (int m = 0; m < 4; ++m) {
            const int mm = m0 + m;
            const int cm = cs[mm];
            float s;
            if (cm <= CAP) {
                s = part[mm][0][d] + part[mm][1][d]
                  + part[mm][2][d] + part[mm][3][d];
                s += x[(size_t)(node0 + mm) * DF + d];
            } else {
                // Fallback (statistically never): bitmap rescan.
                s = x[(size_t)(node0 + mm) * DF + d];
                const uint32* r = bm + (size_t)(node0 + mm) * WPR;
                for (int w = 0; w < WPR; ++w) {
                    uint32 word = r[w];
                    int base = w << 5;
                    while (word) {
                        int bit = __ffs(word) - 1; word &= word - 1;
                        s += x[(size_t)(base + bit) * DF + d];
                    }
                }
            }
            agg[mm][d] = s / (float)(cm + 1);
        }
    }
    __syncthreads();

    // Fused linear: thread (h, d) -> out dim d for its 4 nodes.
    {
        const int d = th;
        const float4* Wrow = (const float4*)(W + (size_t)d * DF);
        float bias = b[d];
        float s0 = bias, s1 = bias, s2 = bias, s3 = bias;
        #pragma unroll 8
        for (int c4 = 0; c4 < DF4; ++c4) {
            float4 wv = Wrow[c4];
            float4 g0 = *(const float4*)&agg[m0 + 0][c4 * 4];
            float4 g1 = *(const float4*)&agg[m0 + 1][c4 * 4];
            float4 g2 = *(const float4*)&agg[m0 + 2][c4 * 4];
            float4 g3 = *(const float4*)&agg[m0 + 3][c4 * 4];
            s0 += wv.x * g0.x + wv.y * g0.y + wv.z * g0.z + wv.w * g0.w;
            s1 += wv.x * g1.x + wv.y * g1.y + wv.z * g1.z + wv.w * g1.w;
            s2 += wv.x * g2.x + wv.y * g2.y + wv.z * g2.z + wv.w * g2.w;
            s3 += wv.x * g3.x + wv.y * g3.y + wv.z * g3.z + wv.w * g3.w;
        }
        out[(size_t)(node0 + m0 + 0) * DF + d] = s0;
        out[(size_t)(node0 + m0 + 1) * DF + d] = s1;
        out[(size_t)(node0 + m0 + 2) * DF + d] = s2;
        out[(size_t)(node0 + m0 + 3) * DF + d] = s3;
    }
}

extern "C" void kernel_launch(void* const* d_in, const int* in_sizes, int n_in,
                              void* d_out, int out_size, void* d_ws, size_t ws_size,
                              hipStream_t stream) {
    const float* x = (const float*)d_in[0];
    const int*  ei = (const int*)d_in[1];
    const float* W = (const float*)d_in[2];
    const float* b = (const float*)d_in[3];
    float* out = (float*)d_out;

    char* ws = (char*)d_ws;
    uint32* bm   = (uint32*)ws;
    int*    cnt  = (int*)(ws + CNT_OFF);
    float4* zrow = (float4*)(ws + ZROW_OFF);
    int*    list = (int*)(ws + LIST_OFF);

    const int E = in_sizes[1] / 2;

    // Zero bitmap + cnt + zrow in one contiguous fill (ws is 0xAA-poisoned).
    hipMemsetAsync(d_ws, 0, ZERO_BYTES, stream);

    scatter_dedup<<<dim3((E + 255) / 256), dim3(256), 0, stream>>>(
        ei, E, bm, cnt, list);
    gcn_gather<<<dim3(NNODES / 8), dim3(256), 0, stream>>>(
        x, W, b, bm, cnt, zrow, list, out);
}

// Round 8
// 112.661 us; speedup vs baseline: 1.0028x; 1.0012x over previous
//
#include <hip/hip_runtime.h>

// SimpleGCNConv: out = rownorm(setadj(ei) + I) @ x @ W^T + b
// N=8192, E=262144, D=128, fp32.
// R8: back to R4's proven split (bitmap-only scatter; lists rebuilt
// IN-BLOCK from the bitmap — R5/R7 proved scatter-side list append costs
// +12 us in contended atomics). Fused kernel restructured: ONE WAVE PER
// NODE (M=4 x 64 lanes): wave-private prefix-sum list build, gather with
// 8 float4 loads in flight (lane = (s,c): 2 k-slots x 32 chunks), shfl
// reduce (no part[] LDS, one less barrier), then fused W^T matvec + b.

typedef unsigned int uint32;

#define NNODES 8192
#define DF 128
#define DF4 (DF / 4)
#define WPR 256                 // bitmap words per row
#define CAP 128                 // list cap (deg ~ Poisson(32), max ~70)

#define BM_BYTES  ((size_t)NNODES * WPR * 4)          // 8 MB
#define ZROW_OFF  BM_BYTES                            // 512 B zeros after bm
#define ZERO_BYTES (BM_BYTES + 1024)

__device__ __forceinline__ float4 f4add(float4 a, float4 b) {
    return make_float4(a.x + b.x, a.y + b.y, a.z + b.z, a.w + b.w);
}

// K1: pure dedup scatter (R4's — fast; no list append, no cnt atomics).
__global__ __launch_bounds__(256) void scatter_dedup(
    const int* __restrict__ ei, int E, uint32* __restrict__ bm)
{
    int e = blockIdx.x * 256 + threadIdx.x;
    if (e >= E) return;
    int src = ei[e];
    int dst = ei[E + e];
    atomicOr(&bm[(size_t)src * WPR + (dst >> 5)], 1u << (dst & 31));
}

// K2: 4 nodes/block, one wave per node.
__global__ __launch_bounds__(256, 4) void gcn_fused(
    const float* __restrict__ x, const float* __restrict__ W,
    const float* __restrict__ b, const uint32* __restrict__ bm,
    const float4* __restrict__ zrow, float* __restrict__ out)
{
    __shared__ int   nbr[4][CAP];                     // 2 KB
    __shared__ __align__(16) float agg[4][DF];        // 2 KB

    const int t    = threadIdx.x;
    const int w    = t >> 6;          // wave = node slot 0..3
    const int lane = t & 63;
    const int node0 = blockIdx.x * 4;
    const int node  = node0 + w;

    // ---- Phase A (wave-private): bitmap row -> LDS list via prefix sum.
    const uint32* r = bm + (size_t)node * WPR;
    const uint4 ww = ((const uint4*)r)[lane];         // 4 words/lane
    int cpop = __popc(ww.x) + __popc(ww.y) + __popc(ww.z) + __popc(ww.w);
    int v = cpop;                                     // inclusive scan
    #pragma unroll
    for (int d = 1; d < 64; d <<= 1) {
        int up = __shfl_up(v, d);
        if (lane >= d) v += up;
    }
    int off = v - cpop;                               // exclusive prefix
    const int total = __shfl(v, 63);                  // wave broadcast
    {
        uint32 arr[4] = {ww.x, ww.y, ww.z, ww.w};
        #pragma unroll
        for (int q = 0; q < 4; ++q) {
            uint32 word = arr[q];
            int base = (4 * lane + q) << 5;
            while (word) {
                int bit = __ffs(word) - 1; word &= word - 1;
                if (off < CAP) nbr[w][off] = base + bit;
                off++;
            }
        }
    }
    const int cm = min(total, CAP);
    const int L  = (cm + 15) & ~15;                   // unroll-8 window
    for (int k = cm + lane; k < L; k += 64) nbr[w][k] = -1;
    __syncthreads();                                  // (cheap; safety)

    // ---- Phase B: gather. lane = (s = k-parity slot, c = float4 chunk).
    const int s = lane >> 5, c = lane & 31;
    const float4* x4 = (const float4*)x;
    float4 acc = make_float4(0.f, 0.f, 0.f, 0.f);

    if (total <= CAP) {
        for (int k = s; k < L; k += 16) {             // 8 loads in flight
            int j0 = nbr[w][k],      j1 = nbr[w][k + 2],
                j2 = nbr[w][k + 4],  j3 = nbr[w][k + 6],
                j4 = nbr[w][k + 8],  j5 = nbr[w][k + 10],
                j6 = nbr[w][k + 12], j7 = nbr[w][k + 14];
            const float4* p0 = (j0 >= 0) ? x4 + (size_t)j0 * DF4 + c : zrow + c;
            const float4* p1 = (j1 >= 0) ? x4 + (size_t)j1 * DF4 + c : zrow + c;
            const float4* p2 = (j2 >= 0) ? x4 + (size_t)j2 * DF4 + c : zrow + c;
            const float4* p3 = (j3 >= 0) ? x4 + (size_t)j3 * DF4 + c : zrow + c;
            const float4* p4 = (j4 >= 0) ? x4 + (size_t)j4 * DF4 + c : zrow + c;
            const float4* p5 = (j5 >= 0) ? x4 + (size_t)j5 * DF4 + c : zrow + c;
            const float4* p6 = (j6 >= 0) ? x4 + (size_t)j6 * DF4 + c : zrow + c;
            const float4* p7 = (j7 >= 0) ? x4 + (size_t)j7 * DF4 + c : zrow + c;
            float4 v0 = *p0, v1 = *p1, v2 = *p2, v3 = *p3;
            float4 v4 = *p4, v5 = *p5, v6 = *p6, v7 = *p7;
            acc = f4add(acc, f4add(f4add(v0, v1), f4add(v2, v3)));
            acc = f4add(acc, f4add(f4add(v4, v5), f4add(v6, v7)));
        }
        // Reduce the two k-parity slots (lanes L and L+32, same chunk c).
        acc.x += __shfl_down(acc.x, 32);
        acc.y += __shfl_down(acc.y, 32);
        acc.z += __shfl_down(acc.z, 32);
        acc.w += __shfl_down(acc.w, 32);
    } else if (lane < 32) {
        // Fallback (statistically never): serial bitmap rescan.
        for (int wd = 0; wd < WPR; ++wd) {
            uint32 word = r[wd];
            int base = wd << 5;
            while (word) {
                int bit = __ffs(word) - 1; word &= word - 1;
                acc = f4add(acc, x4[(size_t)(base + bit) * DF4 + c]);
            }
        }
    }

    if (lane < 32) {
        float4 self = x4[(size_t)node * DF4 + c];     // self-loop on top
        float inv = 1.0f / (float)(total + 1);
        float4 a = f4add(acc, self);
        *(float4*)&agg[w][c * 4] =
            make_float4(a.x * inv, a.y * inv, a.z * inv, a.w * inv);
    }
    __syncthreads();

    // ---- Phase C: fused linear. thread t -> out dim d for 2 nodes.
    {
        const int d = t & 127, h = t >> 7;            // nodes 2h, 2h+1
        const float4* Wrow = (const float4*)(W + (size_t)d * DF);
        float bias = b[d];
        float s0 = bias, s1 = bias;
        #pragma unroll 8
        for (int c4 = 0; c4 < DF4; ++c4) {
            float4 wv = Wrow[c4];
            float4 g0 = *(const float4*)&agg[2 * h + 0][c4 * 4];
            float4 g1 = *(const float4*)&agg[2 * h + 1][c4 * 4];
            s0 += wv.x * g0.x + wv.y * g0.y + wv.z * g0.z + wv.w * g0.w;
            s1 += wv.x * g1.x + wv.y * g1.y + wv.z * g1.z + wv.w * g1.w;
        }
        out[(size_t)(node0 + 2 * h + 0) * DF + d] = s0;
        out[(size_t)(node0 + 2 * h + 1) * DF + d] = s1;
    }
}

extern "C" void kernel_launch(void* const* d_in, const int* in_sizes, int n_in,
                              void* d_out, int out_size, void* d_ws, size_t ws_size,
                              hipStream_t stream) {
    const float* x = (const float*)d_in[0];
    const int*  ei = (const int*)d_in[1];
    const float* W = (const float*)d_in[2];
    const float* b = (const float*)d_in[3];
    float* out = (float*)d_out;

    uint32* bm   = (uint32*)d_ws;
    float4* zrow = (float4*)((char*)d_ws + ZROW_OFF);
    const int E = in_sizes[1] / 2;

    // Zero bitmap + zero-row (ws is 0xAA-poisoned before every launch).
    hipMemsetAsync(d_ws, 0, ZERO_BYTES, stream);

    scatter_dedup<<<dim3((E + 255) / 256), dim3(256), 0, stream>>>(ei, E, bm);
    gcn_fused<<<dim3(NNODES / 4), dim3(256), 0, stream>>>(
        x, W, b, bm, zrow, out);
}

// Round 9
// 100.730 us; speedup vs baseline: 1.1216x; 1.1184x over previous
//
#include <hip/hip_runtime.h>

// SimpleGCNConv: out = rownorm(setadj(ei) + I) @ x @ W^T + b
// N=8192, E=262144, D=128, fp32.
// R9: combine the proven halves of R5 and R8.
//   out = D^-1 (A+I) (x W^T) + b   (associativity: GEMM first, then gather)
//   K0 memset: bitmap (8 MB) + zrow (contiguous)
//   K1 scatter (bitmap-only atomicOr — R5/R7 proved list-append atomics
//      cost +12 us) + spare blocks transpose W -> Wt
//   K2 z = x @ Wt (R5's node_gemm, passed correctness, ~3.5 us)
//   K3 gather: ONE WAVE PER NODE, barrier-free (LDS list is wave-private),
//      8 z-row loads in flight, shfl fold, normalize + bias, float4 store.
//      No Phase C (R8's 42.7 us kernel spent its time on the per-block
//      W matvec chain + doubled W traffic — all deleted here).

typedef unsigned int uint32;

#define NNODES 8192
#define DF 128
#define DF4 (DF / 4)
#define WPR 256                 // bitmap words per row
#define CAP 128                 // list cap (deg ~ Poisson(32), max ~70)

#define BM_BYTES  ((size_t)NNODES * WPR * 4)          // 8 MB
#define ZROW_OFF  BM_BYTES                            // 512 B zeros
#define WT_OFF    (ZROW_OFF + 1024)
#define Z_OFF     (WT_OFF + (size_t)DF * DF * 4)      // z: 4 MB
#define ZERO_BYTES (BM_BYTES + 1024)                  // memset bm+zrow

__device__ __forceinline__ float4 f4add(float4 a, float4 b) {
    return make_float4(a.x + b.x, a.y + b.y, a.z + b.z, a.w + b.w);
}

// K1: dedup scatter (blocks [0,nsb)) + W transpose (blocks [nsb,nsb+16)).
__global__ __launch_bounds__(256) void scatter_wt(
    const int* __restrict__ ei, int E, const float* __restrict__ W,
    uint32* __restrict__ bm, float* __restrict__ Wt)
{
    const int blk = blockIdx.x, t = threadIdx.x;
    const int nsb = (E + 255) >> 8;
    if (blk < nsb) {
        int e = blk * 256 + t;
        if (e < E) {
            int src = ei[e];
            int dst = ei[E + e];
            atomicOr(&bm[(size_t)src * WPR + (dst >> 5)], 1u << (dst & 31));
        }
    } else {
        // Wt[k*DF+d] = W[d*DF+k]
        for (int i = (blk - nsb) * 256 + t; i < DF * DF; i += 16 * 256) {
            int k = i >> 7, d = i & (DF - 1);
            Wt[i] = W[d * DF + k];
        }
    }
}

// K2: z[n][d] = sum_k x[n][k] * Wt[k][d].  32 nodes/block, 256 blocks.
__global__ __launch_bounds__(256) void node_gemm(
    const float* __restrict__ x, const float* __restrict__ Wt,
    float* __restrict__ z)
{
    __shared__ float xs[32][DF];                      // 16 KB
    const int t = threadIdx.x;
    const int n0 = blockIdx.x * 32;

    const float4* x4 = (const float4*)x + (size_t)n0 * DF4;
    float4* xs4 = (float4*)xs;
    for (int i = t; i < 32 * DF4; i += 256) xs4[i] = x4[i];
    __syncthreads();

    const int c = t & 31;
    const int ng = t >> 5;
    const float4* Wt4 = (const float4*)Wt;

    float4 a0 = make_float4(0, 0, 0, 0), a1 = a0, a2 = a0, a3 = a0;
    #pragma unroll 4
    for (int k = 0; k < DF; ++k) {
        float4 wv = Wt4[k * DF4 + c];                 // coalesced
        float x0 = xs[4 * ng + 0][k];                 // LDS broadcast
        float x1 = xs[4 * ng + 1][k];
        float x2 = xs[4 * ng + 2][k];
        float x3 = xs[4 * ng + 3][k];
        a0.x += x0 * wv.x; a0.y += x0 * wv.y; a0.z += x0 * wv.z; a0.w += x0 * wv.w;
        a1.x += x1 * wv.x; a1.y += x1 * wv.y; a1.z += x1 * wv.z; a1.w += x1 * wv.w;
        a2.x += x2 * wv.x; a2.y += x2 * wv.y; a2.z += x2 * wv.z; a2.w += x2 * wv.w;
        a3.x += x3 * wv.x; a3.y += x3 * wv.y; a3.z += x3 * wv.z; a3.w += x3 * wv.w;
    }
    float4* z4 = (float4*)z;
    z4[(size_t)(n0 + 4 * ng + 0) * DF4 + c] = a0;
    z4[(size_t)(n0 + 4 * ng + 1) * DF4 + c] = a1;
    z4[(size_t)(n0 + 4 * ng + 2) * DF4 + c] = a2;
    z4[(size_t)(n0 + 4 * ng + 3) * DF4 + c] = a3;
}

// K3: one wave per node; barrier-free.
__global__ __launch_bounds__(256) void gather_z(
    const float4* __restrict__ z4, const uint32* __restrict__ bm,
    const float4* __restrict__ zrow, const float* __restrict__ b,
    float* __restrict__ out)
{
    __shared__ int nbr[4][CAP];                       // 2 KB, wave-private

    const int t    = threadIdx.x;
    const int w    = t >> 6;
    const int lane = t & 63;
    const int node = blockIdx.x * 4 + w;

    // Phase A (wave-private): bitmap row -> LDS list via prefix sum.
    const uint32* r = bm + (size_t)node * WPR;
    const uint4 ww = ((const uint4*)r)[lane];         // 4 words/lane
    int cpop = __popc(ww.x) + __popc(ww.y) + __popc(ww.z) + __popc(ww.w);
    int v = cpop;
    #pragma unroll
    for (int d = 1; d < 64; d <<= 1) {
        int up = __shfl_up(v, d);
        if (lane >= d) v += up;
    }
    int off = v - cpop;
    const int total = __shfl(v, 63);
    {
        uint32 arr[4] = {ww.x, ww.y, ww.z, ww.w};
        #pragma unroll
        for (int q = 0; q < 4; ++q) {
            uint32 word = arr[q];
            int base = (4 * lane + q) << 5;
            while (word) {
                int bit = __ffs(word) - 1; word &= word - 1;
                if (off < CAP) nbr[w][off] = base + bit;
                off++;
            }
        }
    }
    const int cm = min(total, CAP);
    const int L  = (cm + 15) & ~15;                   // unroll-8 window
    for (int k = cm + lane; k < L; k += 64) nbr[w][k] = -1;
    // No __syncthreads: nbr[w] only touched by wave w (lgkmcnt handles it).

    // Phase B: gather z rows. lane = (s = k parity, c = float4 chunk).
    const int s = lane >> 5, c = lane & 31;
    float4 acc = make_float4(0.f, 0.f, 0.f, 0.f);

    if (total <= CAP) {
        for (int k = s; k < L; k += 16) {             // 8 loads in flight
            int j0 = nbr[w][k],      j1 = nbr[w][k + 2],
                j2 = nbr[w][k + 4],  j3 = nbr[w][k + 6],
                j4 = nbr[w][k + 8],  j5 = nbr[w][k + 10],
                j6 = nbr[w][k + 12], j7 = nbr[w][k + 14];
            const float4* p0 = (j0 >= 0) ? z4 + (size_t)j0 * DF4 + c : zrow + c;
            const float4* p1 = (j1 >= 0) ? z4 + (size_t)j1 * DF4 + c : zrow + c;
            const float4* p2 = (j2 >= 0) ? z4 + (size_t)j2 * DF4 + c : zrow + c;
            const float4* p3 = (j3 >= 0) ? z4 + (size_t)j3 * DF4 + c : zrow + c;
            const float4* p4 = (j4 >= 0) ? z4 + (size_t)j4 * DF4 + c : zrow + c;
            const float4* p5 = (j5 >= 0) ? z4 + (size_t)j5 * DF4 + c : zrow + c;
            const float4* p6 = (j6 >= 0) ? z4 + (size_t)j6 * DF4 + c : zrow + c;
            const float4* p7 = (j7 >= 0) ? z4 + (size_t)j7 * DF4 + c : zrow + c;
            float4 v0 = *p0, v1 = *p1, v2 = *p2, v3 = *p3;
            float4 v4 = *p4, v5 = *p5, v6 = *p6, v7 = *p7;
            acc = f4add(acc, f4add(f4add(v0, v1), f4add(v2, v3)));
            acc = f4add(acc, f4add(f4add(v4, v5), f4add(v6, v7)));
        }
        acc.x += __shfl_down(acc.x, 32);
        acc.y += __shfl_down(acc.y, 32);
        acc.z += __shfl_down(acc.z, 32);
        acc.w += __shfl_down(acc.w, 32);
    } else if (lane < 32) {
        // Fallback (statistically never): serial bitmap rescan.
        for (int wd = 0; wd < WPR; ++wd) {
            uint32 word = r[wd];
            int base = wd << 5;
            while (word) {
                int bit = __ffs(word) - 1; word &= word - 1;
                acc = f4add(acc, z4[(size_t)(base + bit) * DF4 + c]);
            }
        }
    }

    // Epilogue: +self (eye on top), normalize, +bias, store.
    if (lane < 32) {
        float4 self = z4[(size_t)node * DF4 + c];
        float4 bb = ((const float4*)b)[c];
        float inv = 1.0f / (float)(total + 1);
        float4 a = f4add(acc, self);
        ((float4*)out)[(size_t)node * DF4 + c] =
            make_float4(a.x * inv + bb.x, a.y * inv + bb.y,
                        a.z * inv + bb.z, a.w * inv + bb.w);
    }
}

extern "C" void kernel_launch(void* const* d_in, const int* in_sizes, int n_in,
                              void* d_out, int out_size, void* d_ws, size_t ws_size,
                              hipStream_t stream) {
    const float* x = (const float*)d_in[0];
    const int*  ei = (const int*)d_in[1];
    const float* W = (const float*)d_in[2];
    const float* b = (const float*)d_in[3];
    float* out = (float*)d_out;

    char* ws = (char*)d_ws;
    uint32* bm   = (uint32*)ws;
    float4* zrow = (float4*)(ws + ZROW_OFF);
    float*  Wt   = (float*)(ws + WT_OFF);
    float*  z    = (float*)(ws + Z_OFF);

    const int E = in_sizes[1] / 2;
    const int nsb = (E + 255) / 256;

    // Zero bitmap + zrow (ws is 0xAA-poisoned before every launch).
    hipMemsetAsync(d_ws, 0, ZERO_BYTES, stream);

    scatter_wt<<<dim3(nsb + 16), dim3(256), 0, stream>>>(ei, E, W, bm, Wt);
    node_gemm<<<dim3(NNODES / 32), dim3(256), 0, stream>>>(x, Wt, z);
    gather_z<<<dim3(NNODES / 4), dim3(256), 0, stream>>>(
        (const float4*)z, bm, zrow, b, out);
}